// Round 2
// baseline (63.278 us; speedup 1.0000x reference)
//
#include <hip/hip_runtime.h>
#include <hip/hip_bf16.h>

// Problem constants (hardcoded in the reference)
#define B_SZ 512
#define D_SZ 1024
#define NK 160
#define NCOL 480          // NK*3
#define OUTW 1184         // D + NK
#define LOG2E 1.44269504088896340736f

__device__ __forceinline__ unsigned int f32_bf16_rne(float f) {
    unsigned int u = __float_as_uint(f);
    u += 0x7fffu + ((u >> 16) & 1u);   // round-to-nearest-even on bf16 boundary
    return u >> 16;
}

// ---------------- Pack: inT2[kkp][i] = bf16(A[i][2kkp]) | bf16(A[i][2kkp+1])<<16
// Scattered 8B reads (L2-absorbed), fully coalesced 16B writes.
__global__ __launch_bounds__(256) void mbd_pack_kernel(
    const float* __restrict__ A, unsigned int* __restrict__ inT2)
{
    const int gid = blockIdx.x * 256 + threadIdx.x;  // 0..65535
    const int kkp = gid >> 7;                        // 0..511
    const int i0  = (gid & 127) * 4;                 // 0..508
    unsigned int o[4];
#pragma unroll
    for (int r = 0; r < 4; ++r) {
        const float2 v = *reinterpret_cast<const float2*>(&A[(i0 + r) * D_SZ + 2 * kkp]);
        o[r] = f32_bf16_rne(v.x) | (f32_bf16_rne(v.y) << 16);
    }
    *reinterpret_cast<uint4*>(&inT2[kkp * B_SZ + i0]) = make_uint4(o[0], o[1], o[2], o[3]);
}

// ---------------- Act (GEMV-style): act4[k][i] = (inputs[i,:].W[:,3k..3k+2] + b)*log2e
// Grid (160,4) x 512 thr. Per block: 128 i-rows, 4-way K-split across wave pairs.
// x-stream: coalesced 4B/lane loads; W: wave-uniform addresses -> scalar loads.
__global__ __launch_bounds__(512) void mbd_act_kernel(
    const unsigned int* __restrict__ inT2, const float* __restrict__ W,
    const float* __restrict__ bias, float4* __restrict__ act4)
{
    __shared__ float4 p_lds[512];
    const int k = blockIdx.x;                         // 0..159
    const int h = blockIdx.y;                         // 0..3 (i-chunk)
    const int t = threadIdx.x;                        // 0..511
    const int i = h * 128 + (t & 127);
    const int kq = __builtin_amdgcn_readfirstlane(t >> 7);  // 0..3, wave-uniform
    const int c0 = 3 * k;

    float a0 = 0.f, a1 = 0.f, a2 = 0.f;
    const unsigned int* __restrict__ xp = inT2 + i;   // + kkp*B_SZ per step
    const int kkp0 = kq * 128;
#pragma unroll 4
    for (int jj = 0; jj < 128; ++jj) {
        const int kkp = kkp0 + jj;
        const unsigned int u = xp[kkp * B_SZ];        // 2 bf16 inputs for row i
        const float x0 = __uint_as_float(u << 16);            // kk = 2*kkp
        const float x1 = __uint_as_float(u & 0xffff0000u);    // kk = 2*kkp+1
        const int kk = 2 * kkp;
        const float* __restrict__ w0 = W + kk * NCOL + c0;    // uniform -> s_load
        const float* __restrict__ w1 = w0 + NCOL;
        a0 = fmaf(x0, w0[0], a0); a1 = fmaf(x0, w0[1], a1); a2 = fmaf(x0, w0[2], a2);
        a0 = fmaf(x1, w1[0], a0); a1 = fmaf(x1, w1[1], a1); a2 = fmaf(x1, w1[2], a2);
    }
    p_lds[t] = make_float4(a0, a1, a2, 0.f);
    __syncthreads();
    if (t < 128) {
        const float4 s0 = p_lds[t];
        const float4 s1 = p_lds[t + 128];
        const float4 s2 = p_lds[t + 256];
        const float4 s3 = p_lds[t + 384];
        const float r0 = (s0.x + s1.x + s2.x + s3.x + bias[c0 + 0]) * LOG2E;
        const float r1 = (s0.y + s1.y + s2.y + s3.y + bias[c0 + 1]) * LOG2E;
        const float r2 = (s0.z + s1.z + s2.z + s3.z + bias[c0 + 2]) * LOG2E;
        act4[k * B_SZ + i] = make_float4(r0, r1, r2, 0.f);
    }
}

// ---------------- Pairwise: grid (160,8) x 64 thr. acts pre-scaled by log2e,
// so exp(-d) == exp2(-d_scaled): no per-iteration multiply, raw v_exp_f32.
__global__ __launch_bounds__(64) void mbd_pairwise_kernel(
    const float4* __restrict__ act4, float* __restrict__ out)
{
    __shared__ float4 as4[B_SZ];
    const int k = blockIdx.x;          // 0..159
    const int q = blockIdx.y;          // 0..7 (i-chunk)
    const int t = threadIdx.x;         // 0..63
#pragma unroll
    for (int s = 0; s < 8; ++s)
        as4[t + s * 64] = act4[k * B_SZ + t + s * 64];
    __syncthreads();

    const int i = q * 64 + t;
    const float4 ai = as4[i];
    float acc = 0.f;
#pragma unroll 8
    for (int j = 0; j < B_SZ; ++j) {
        const float4 av = as4[j];      // broadcast ds_read_b128
        const float d = fabsf(ai.x - av.x) + fabsf(ai.y - av.y) + fabsf(ai.z - av.z);
        acc += __builtin_amdgcn_exp2f(-d);
    }
    out[i * OUTW + D_SZ + k] = acc;
}

// ---------------- Copy inputs -> out[:, 0:1024], float4 coalesced
__global__ __launch_bounds__(256) void mbd_copy_kernel(
    const float* __restrict__ in, float* __restrict__ out)
{
    const int i = blockIdx.x;          // row 0..511
    const int t = threadIdx.x;         // 0..255
    const float4 v = *reinterpret_cast<const float4*>(&in[i * D_SZ + t * 4]);
    *reinterpret_cast<float4*>(&out[i * OUTW + t * 4]) = v;
}

extern "C" void kernel_launch(void* const* d_in, const int* in_sizes, int n_in,
                              void* d_out, int out_size, void* d_ws, size_t ws_size,
                              hipStream_t stream)
{
    const float* inputs = (const float*)d_in[0];   // [512,1024] f32
    const float* W      = (const float*)d_in[1];   // [1024,480] f32
    const float* bias   = (const float*)d_in[2];   // [480] f32
    float* out = (float*)d_out;                    // [512,1184] f32

    unsigned int* inT2 = (unsigned int*)d_ws;                      // 1 MB
    float4* act4 = (float4*)((char*)d_ws + (size_t)(1 << 20));     // 1.31 MB

    mbd_pack_kernel<<<256, 256, 0, stream>>>(inputs, inT2);
    mbd_act_kernel<<<dim3(NK, 4), 512, 0, stream>>>(inT2, W, bias, act4);
    mbd_pairwise_kernel<<<dim3(NK, 8), 64, 0, stream>>>(act4, out);
    mbd_copy_kernel<<<B_SZ, 256, 0, stream>>>(inputs, out);
}

// Round 3
// 36.636 us; speedup vs baseline: 1.7272x; 1.7272x over previous
//
#include <hip/hip_runtime.h>
#include <hip/hip_bf16.h>

// Problem constants (hardcoded in the reference)
#define B_SZ 512
#define D_SZ 1024
#define NK 160
#define NCOL 480          // NK*3
#define OUTW 1184         // D + NK
#define LOG2E 1.44269504088896340736f

typedef __attribute__((ext_vector_type(8))) short bf16x8;
typedef __attribute__((ext_vector_type(4))) float f32x4;

__device__ __forceinline__ unsigned int f32_bf16_rne(float f) {
    unsigned int u = __float_as_uint(f);
    u += 0x7fffu + ((u >> 16) & 1u);   // round-to-nearest-even at bf16 boundary
    return u >> 16;
}
__device__ __forceinline__ float bf16u_to_f32(unsigned int h) {
    return __uint_as_float(h << 16);
}

// ---------------- Prep: (a) A -> bf16 row-major + copy A -> out[:,0:1024]
//                        (b) W -> Wt hi/lo bf16, layout [col][k] (K-contiguous)
__global__ __launch_bounds__(256) void mbd_prep_kernel(
    const float* __restrict__ A,        // [512][1024]
    const float* __restrict__ W,        // [1024][480]
    unsigned int* __restrict__ A2u,     // [512][512] bf16-pairs == [512][1024] bf16
    unsigned int* __restrict__ Whi_u,   // [480][512] bf16-pairs == [480][1024] bf16
    unsigned int* __restrict__ Wlo_u,   // residual (W - bf16(W)) in bf16
    float* __restrict__ out)            // [512][1184]
{
    const int b = blockIdx.x, t = threadIdx.x;
    if (b < 128) {
        // rows 4b..4b+3: coalesced float4 read, copy + bf16 pack
#pragma unroll
        for (int s = 0; s < 4; ++s) {
            const int idx = s * 256 + t;
            const int r = 4 * b + (idx >> 8);
            const int c4 = (idx & 255) * 4;
            const float4 v = *reinterpret_cast<const float4*>(&A[r * D_SZ + c4]);
            *reinterpret_cast<float4*>(&out[r * OUTW + c4]) = v;
            const unsigned int p0 = f32_bf16_rne(v.x) | (f32_bf16_rne(v.y) << 16);
            const unsigned int p1 = f32_bf16_rne(v.z) | (f32_bf16_rne(v.w) << 16);
            *reinterpret_cast<uint2*>(&A2u[r * 512 + (c4 >> 1)]) = make_uint2(p0, p1);
        }
    } else {
        // W transpose + hi/lo split: one (col, k-pair) per thread
        const int gid = (b - 128) * 256 + t;     // 0..245759
        const int col = gid >> 9;                // 0..479
        const int kkp = gid & 511;               // 0..511
        const float w0 = W[(2 * kkp + 0) * NCOL + col];
        const float w1 = W[(2 * kkp + 1) * NCOL + col];
        const unsigned int h0 = f32_bf16_rne(w0), h1 = f32_bf16_rne(w1);
        const unsigned int l0 = f32_bf16_rne(w0 - bf16u_to_f32(h0));
        const unsigned int l1 = f32_bf16_rne(w1 - bf16u_to_f32(h1));
        Whi_u[col * 512 + kkp] = h0 | (h1 << 16);
        Wlo_u[col * 512 + kkp] = l0 | (l1 << 16);
    }
}

// ---------------- MFMA GEMM: act_t[col][i] = (A[i,:].W[:,col] + b[col]) * log2e
// Tile 64(M) x 16(N), K-chunk 128. 4 waves: wave w owns rows 16w..16w+15.
// LDS rows are 256B; frag ds_read_b128 would 16-way-conflict, so stage with
// pre-swizzled global source (kbyte ^= (row&7)<<4) and read with same XOR.
__global__ __launch_bounds__(256) void mbd_mfma_kernel(
    const unsigned short* __restrict__ A2,    // [512][1024] bf16
    const unsigned short* __restrict__ Whi,   // [480][1024] bf16
    const unsigned short* __restrict__ Wlo,   // [480][1024] bf16
    const float* __restrict__ bias,           // [480]
    float* __restrict__ act_t)                // [480][512] f32 (pre-scaled)
{
    __shared__ char lds[24576];
    char* a_lds  = lds;             // [64 rows][256B]
    char* bh_lds = lds + 16384;     // [16 cols][256B]
    char* bl_lds = lds + 20480;     // [16 cols][256B]

    const int bm = blockIdx.x;      // 0..7
    const int bn = blockIdx.y;      // 0..29
    const int tid = threadIdx.x;
    const int w = __builtin_amdgcn_readfirstlane(tid >> 6);  // wave id (uniform!)
    const int l = tid & 63;
    const int lhi = l >> 4, llo = l & 15;
    const int i0 = bm * 64, c0 = bn * 16;

    f32x4 acc = {0.f, 0.f, 0.f, 0.f};

    for (int k0 = 0; k0 < D_SZ; k0 += 128) {
        __syncthreads();   // previous chunk's compute done before overwrite
        // ---- stage A: wave w stages its 16 rows (4 insts x 4rows x 256B)
#pragma unroll
        for (int s = 0; s < 4; ++s) {
            const int row = 16 * w + 4 * s + lhi;
            const int kbs = (llo * 16) ^ ((row & 7) << 4);
            const unsigned short* src = A2 + (size_t)(i0 + row) * D_SZ + k0 + (kbs >> 1);
            __builtin_amdgcn_global_load_lds(
                (const __attribute__((address_space(1))) void*)src,
                (__attribute__((address_space(3))) void*)(a_lds + w * 4096 + s * 1024),
                16, 0, 0);
        }
        // ---- stage B: waves 0-1 -> hi, waves 2-3 -> lo (2 insts each)
        {
            const unsigned short* Wsrc = (w >> 1) ? Wlo : Whi;
            char* bdst = (w >> 1) ? bl_lds : bh_lds;
            const int w2 = w & 1;
#pragma unroll
            for (int s = 0; s < 2; ++s) {
                const int colin = 8 * w2 + 4 * s + lhi;   // 0..15
                const int kbs = (llo * 16) ^ ((colin & 7) << 4);
                const unsigned short* src = Wsrc + (size_t)(c0 + colin) * D_SZ + k0 + (kbs >> 1);
                __builtin_amdgcn_global_load_lds(
                    (const __attribute__((address_space(1))) void*)src,
                    (__attribute__((address_space(3))) void*)(bdst + w2 * 2048 + s * 1024),
                    16, 0, 0);
            }
        }
        asm volatile("s_waitcnt vmcnt(0)");
        __syncthreads();
        // ---- compute: 4 K-slices x (1 A-frag + 2 B-frags + 2 MFMA)
#pragma unroll
        for (int ks = 0; ks < 4; ++ks) {
            const int koff = (lhi * 16 + ks * 64) ^ ((llo & 7) << 4);
            const bf16x8 af = *reinterpret_cast<const bf16x8*>(a_lds + (16 * w + llo) * 256 + koff);
            const bf16x8 bh = *reinterpret_cast<const bf16x8*>(bh_lds + llo * 256 + koff);
            const bf16x8 bl = *reinterpret_cast<const bf16x8*>(bl_lds + llo * 256 + koff);
            acc = __builtin_amdgcn_mfma_f32_16x16x32_bf16(af, bh, acc, 0, 0, 0);
            acc = __builtin_amdgcn_mfma_f32_16x16x32_bf16(af, bl, acc, 0, 0, 0);
        }
    }
    // ---- epilogue: C/D layout col=lane&15, row=(lane>>4)*4+reg
    const int col = c0 + llo;
    const float bs = bias[col];
    float4 o;
    o.x = (acc[0] + bs) * LOG2E;
    o.y = (acc[1] + bs) * LOG2E;
    o.z = (acc[2] + bs) * LOG2E;
    o.w = (acc[3] + bs) * LOG2E;
    *reinterpret_cast<float4*>(&act_t[(size_t)col * B_SZ + i0 + 16 * w + lhi * 4]) = o;
}

// ---------------- Pairwise: grid (160,4) x 128 thr (640 blocks -> all CUs).
// acts pre-scaled by log2e so exp(-d) == exp2(-d'). j==i term gives +1 (matches ref).
__global__ __launch_bounds__(128) void mbd_pairwise_kernel(
    const float* __restrict__ act_t,   // [480][512]
    float* __restrict__ out)           // [512][1184]
{
    __shared__ float4 as4[B_SZ];
    const int k = blockIdx.x;          // 0..159
    const int q = blockIdx.y;          // 0..3
    const int t = threadIdx.x;         // 0..127

    const float4 r0 = *reinterpret_cast<const float4*>(&act_t[(3 * k + 0) * B_SZ + t * 4]);
    const float4 r1 = *reinterpret_cast<const float4*>(&act_t[(3 * k + 1) * B_SZ + t * 4]);
    const float4 r2 = *reinterpret_cast<const float4*>(&act_t[(3 * k + 2) * B_SZ + t * 4]);
    as4[t * 4 + 0] = make_float4(r0.x, r1.x, r2.x, 0.f);
    as4[t * 4 + 1] = make_float4(r0.y, r1.y, r2.y, 0.f);
    as4[t * 4 + 2] = make_float4(r0.z, r1.z, r2.z, 0.f);
    as4[t * 4 + 3] = make_float4(r0.w, r1.w, r2.w, 0.f);
    __syncthreads();

    const int i = q * 128 + t;
    const float4 ai = as4[i];
    float acc = 0.f;
#pragma unroll 8
    for (int j = 0; j < B_SZ; ++j) {
        const float4 av = as4[j];      // broadcast ds_read_b128 (free)
        const float d = fabsf(ai.x - av.x) + fabsf(ai.y - av.y) + fabsf(ai.z - av.z);
        acc += __builtin_amdgcn_exp2f(-d);
    }
    out[i * OUTW + D_SZ + k] = acc;
}

extern "C" void kernel_launch(void* const* d_in, const int* in_sizes, int n_in,
                              void* d_out, int out_size, void* d_ws, size_t ws_size,
                              hipStream_t stream)
{
    const float* inputs = (const float*)d_in[0];   // [512,1024] f32
    const float* W      = (const float*)d_in[1];   // [1024,480] f32
    const float* bias   = (const float*)d_in[2];   // [480] f32
    float* out = (float*)d_out;                    // [512,1184] f32

    char* ws = (char*)d_ws;
    unsigned int* A2u   = (unsigned int*)(ws);                        // 1,048,576 B
    unsigned int* Whi_u = (unsigned int*)(ws + 1048576);              //   983,040 B
    unsigned int* Wlo_u = (unsigned int*)(ws + 1048576 + 983040);     //   983,040 B
    float*        act_t = (float*)      (ws + 1048576 + 2 * 983040);  //   983,040 B

    mbd_prep_kernel<<<1088, 256, 0, stream>>>(inputs, W, A2u, Whi_u, Wlo_u, out);
    mbd_mfma_kernel<<<dim3(8, 30), 256, 0, stream>>>(
        (const unsigned short*)A2u, (const unsigned short*)Whi_u,
        (const unsigned short*)Wlo_u, bias, act_t);
    mbd_pairwise_kernel<<<dim3(NK, 4), 128, 0, stream>>>(act_t, out);
}

// Round 4
// 35.065 us; speedup vs baseline: 1.8046x; 1.0448x over previous
//
#include <hip/hip_runtime.h>
#include <hip/hip_bf16.h>

// Problem constants (hardcoded in the reference)
#define B_SZ 512
#define D_SZ 1024
#define NK 160
#define NCOL 480          // NK*3
#define OUTW 1184         // D + NK
#define LOG2E 1.44269504088896340736f

typedef __attribute__((ext_vector_type(8))) short bf16x8;
typedef __attribute__((ext_vector_type(4))) float f32x4;

__device__ __forceinline__ unsigned int f32_bf16_rne(float f) {
    unsigned int u = __float_as_uint(f);
    u += 0x7fffu + ((u >> 16) & 1u);   // round-to-nearest-even at bf16 boundary
    return u >> 16;
}
__device__ __forceinline__ float bf16u_to_f32(unsigned int h) {
    return __uint_as_float(h << 16);
}

// ---------------- Prep:
// blocks 0..511   : row b of A -> out[:,0:1024] copy + bf16 pack (coalesced)
// blocks 512..751 : 64k x 32col tile of W -> transposed hi/lo bf16 (coalesced)
__global__ __launch_bounds__(256) void mbd_prep_kernel(
    const float* __restrict__ A,        // [512][1024]
    const float* __restrict__ W,        // [1024][480]
    unsigned int* __restrict__ A2u,     // [512][512] bf16-pairs
    unsigned int* __restrict__ Whi_u,   // [480][512] bf16-pairs, layout [col][k]
    unsigned int* __restrict__ Wlo_u,   // residual (W - bf16(W)) in bf16
    float* __restrict__ out)            // [512][1184]
{
    __shared__ float lds_t[64][33];     // W tile, padded
    const int b = blockIdx.x, t = threadIdx.x;
    if (b < 512) {
        const int row = b;
        const float4 v = *reinterpret_cast<const float4*>(&A[row * D_SZ + t * 4]);
        *reinterpret_cast<float4*>(&out[row * OUTW + t * 4]) = v;
        const unsigned int p0 = f32_bf16_rne(v.x) | (f32_bf16_rne(v.y) << 16);
        const unsigned int p1 = f32_bf16_rne(v.z) | (f32_bf16_rne(v.w) << 16);
        *reinterpret_cast<uint2*>(&A2u[row * 512 + 2 * t]) = make_uint2(p0, p1);
    } else {
        const int bw = b - 512;          // 0..239
        const int c0 = (bw % 15) * 32;   // col tile
        const int k0 = (bw / 15) * 64;   // k tile
        // read 64 k-rows x 32 cols, coalesced
#pragma unroll
        for (int p = 0; p < 8; ++p) {
            const int k = p * 8 + (t >> 5);
            lds_t[k][t & 31] = W[(k0 + k) * NCOL + c0 + (t & 31)];
        }
        __syncthreads();
        // write transposed [col][kkp], hi/lo split, coalesced along kkp
#pragma unroll
        for (int p = 0; p < 4; ++p) {
            const int flat = p * 256 + t;       // 0..1023
            const int col = flat >> 5;          // 0..31
            const int kkp = flat & 31;          // 0..31
            const float w0 = lds_t[2 * kkp + 0][col];
            const float w1 = lds_t[2 * kkp + 1][col];
            const unsigned int h0 = f32_bf16_rne(w0), h1 = f32_bf16_rne(w1);
            const unsigned int l0 = f32_bf16_rne(w0 - bf16u_to_f32(h0));
            const unsigned int l1 = f32_bf16_rne(w1 - bf16u_to_f32(h1));
            const int idx = (c0 + col) * 512 + (k0 >> 1) + kkp;
            Whi_u[idx] = h0 | (h1 << 16);
            Wlo_u[idx] = l0 | (l1 << 16);
        }
    }
}

// ---------------- MFMA GEMM, double-buffered.
// Tile 32(M) x 16(N), K-chunk 128, grid (16,30), 128 thr (2 waves).
// act_t[col][i] = (A[i,:].W[:,col] + b[col]) * log2e, f32 planes [480][512].
__global__ __launch_bounds__(128) void mbd_mfma_kernel(
    const unsigned short* __restrict__ A2,    // [512][1024] bf16
    const unsigned short* __restrict__ Whi,   // [480][1024] bf16
    const unsigned short* __restrict__ Wlo,   // [480][1024] bf16
    const float* __restrict__ bias,           // [480]
    float* __restrict__ act_t)                // [480][512] f32 (pre-scaled)
{
    __shared__ char lds[2][16384];  // per buf: A[32][256B] @0, Bh[16][256B] @8192, Bl @12288

    const int bm = blockIdx.x;      // 0..15 (32 rows)
    const int bn = blockIdx.y;      // 0..29 (16 cols)
    const int tid = threadIdx.x;
    const int w = __builtin_amdgcn_readfirstlane(tid >> 6);  // 0..1 (uniform)
    const int l = tid & 63;
    const int lhi = l >> 4, llo = l & 15;
    const int i0 = bm * 32, c0 = bn * 16;

    const unsigned short* __restrict__ Wp = w ? Wlo : Whi;
    const int boff = w ? 12288 : 8192;

    f32x4 acc = {0.f, 0.f, 0.f, 0.f};

    // stage(buf, k0): wave w stages its 16 A-rows + its 16 B-cols (hi or lo)
    auto stage = [&](int buf, int k0) {
#pragma unroll
        for (int s = 0; s < 4; ++s) {
            const int rsub = 4 * s + lhi;                    // 0..15
            const int row = 16 * w + rsub;
            const int kbs = (llo * 16) ^ ((row & 7) << 4);
            const unsigned short* src = A2 + (size_t)(i0 + row) * D_SZ + k0 + (kbs >> 1);
            __builtin_amdgcn_global_load_lds(
                (const __attribute__((address_space(1))) void*)src,
                (__attribute__((address_space(3))) void*)(&lds[buf][w * 4096 + s * 1024]),
                16, 0, 0);
        }
#pragma unroll
        for (int s = 0; s < 4; ++s) {
            const int colin = 4 * s + lhi;                   // 0..15
            const int kbs = (llo * 16) ^ ((colin & 7) << 4);
            const unsigned short* src = Wp + (size_t)(c0 + colin) * D_SZ + k0 + (kbs >> 1);
            __builtin_amdgcn_global_load_lds(
                (const __attribute__((address_space(1))) void*)src,
                (__attribute__((address_space(3))) void*)(&lds[buf][boff + s * 1024]),
                16, 0, 0);
        }
    };

    stage(0, 0);
    asm volatile("s_waitcnt vmcnt(0)" ::: "memory");
    __syncthreads();

    for (int t = 0; t < 8; ++t) {
        if (t < 7) stage((t + 1) & 1, (t + 1) * 128);
        const int buf = t & 1;
#pragma unroll
        for (int ks = 0; ks < 4; ++ks) {
            const int koff = (lhi * 16 + ks * 64) ^ ((llo & 7) << 4);
            const bf16x8 af = *reinterpret_cast<const bf16x8*>(&lds[buf][(16 * w + llo) * 256 + koff]);
            const bf16x8 bh = *reinterpret_cast<const bf16x8*>(&lds[buf][8192 + llo * 256 + koff]);
            const bf16x8 bl = *reinterpret_cast<const bf16x8*>(&lds[buf][12288 + llo * 256 + koff]);
            acc = __builtin_amdgcn_mfma_f32_16x16x32_bf16(af, bh, acc, 0, 0, 0);
            acc = __builtin_amdgcn_mfma_f32_16x16x32_bf16(af, bl, acc, 0, 0, 0);
        }
        if (t < 7) {
            asm volatile("s_waitcnt vmcnt(0)" ::: "memory");
            __syncthreads();
        }
    }

    // epilogue: C/D layout col=lane&15, row=(lane>>4)*4+reg
    const int col = c0 + llo;
    const float bs = bias[col];
    float4 o;
    o.x = (acc[0] + bs) * LOG2E;
    o.y = (acc[1] + bs) * LOG2E;
    o.z = (acc[2] + bs) * LOG2E;
    o.w = (acc[3] + bs) * LOG2E;
    *reinterpret_cast<float4*>(&act_t[(size_t)col * B_SZ + i0 + 16 * w + lhi * 4]) = o;
}

// ---------------- Pairwise: grid (160,8) x 64 thr = 1280 single-wave blocks.
// acts pre-scaled by log2e so exp(-d) == exp2(-d'). j==i term gives +1 (matches ref).
__global__ __launch_bounds__(64) void mbd_pairwise_kernel(
    const float* __restrict__ act_t,   // [480][512] planes
    float* __restrict__ out)           // [512][1184]
{
    __shared__ float4 as4[B_SZ];
    const int k = blockIdx.x;          // 0..159
    const int q = blockIdx.y;          // 0..7
    const int t = threadIdx.x;         // 0..63

    const float* __restrict__ p0 = act_t + (3 * k + 0) * B_SZ;
    const float* __restrict__ p1 = act_t + (3 * k + 1) * B_SZ;
    const float* __restrict__ p2 = act_t + (3 * k + 2) * B_SZ;
#pragma unroll
    for (int s = 0; s < 8; ++s) {
        const int idx = s * 64 + t;
        as4[idx] = make_float4(p0[idx], p1[idx], p2[idx], 0.f);
    }
    __syncthreads();

    const int i = q * 64 + t;
    const float4 ai = as4[i];
    float acc = 0.f;
#pragma unroll 8
    for (int j = 0; j < B_SZ; ++j) {
        const float4 av = as4[j];      // broadcast ds_read_b128
        const float d = fabsf(ai.x - av.x) + fabsf(ai.y - av.y) + fabsf(ai.z - av.z);
        acc += __builtin_amdgcn_exp2f(-d);
    }
    out[i * OUTW + D_SZ + k] = acc;
}

extern "C" void kernel_launch(void* const* d_in, const int* in_sizes, int n_in,
                              void* d_out, int out_size, void* d_ws, size_t ws_size,
                              hipStream_t stream)
{
    const float* inputs = (const float*)d_in[0];   // [512,1024] f32
    const float* W      = (const float*)d_in[1];   // [1024,480] f32
    const float* bias   = (const float*)d_in[2];   // [480] f32
    float* out = (float*)d_out;                    // [512,1184] f32

    char* ws = (char*)d_ws;
    unsigned int* A2u   = (unsigned int*)(ws);                        // 1,048,576 B
    unsigned int* Whi_u = (unsigned int*)(ws + 1048576);              //   983,040 B
    unsigned int* Wlo_u = (unsigned int*)(ws + 1048576 + 983040);     //   983,040 B
    float*        act_t = (float*)      (ws + 1048576 + 2 * 983040);  //   983,040 B

    mbd_prep_kernel<<<752, 256, 0, stream>>>(inputs, W, A2u, Whi_u, Wlo_u, out);
    mbd_mfma_kernel<<<dim3(16, 30), 128, 0, stream>>>(
        (const unsigned short*)A2u, (const unsigned short*)Whi_u,
        (const unsigned short*)Wlo_u, bias, act_t);
    mbd_pairwise_kernel<<<dim3(NK, 8), 64, 0, stream>>>(act_t, out);
}